// Round 2
// baseline (114.039 us; speedup 1.0000x reference)
//
#include <hip/hip_runtime.h>
#include <float.h>

// Problem constants (B=8, N=8192, D=3)
#define NB 8
#define NPTS 8192
#define TOTAL (NB * NPTS)            // 65536 adv points
#define BLK 256
#define APT 16                       // adv points per thread (packed as 8 v2f)
#define HALF_APT 8
#define OSPLIT 64                    // ori-dimension split
#define OCHUNK (NPTS / OSPLIT)       // 128 ori points per block (2 KB LDS)
#define ADV_PER_BLOCK (BLK * APT)    // 4096
#define ADV_CHUNKS (NPTS / ADV_PER_BLOCK)  // 2
#define GRID_MAIN (NB * OSPLIT * ADV_CHUNKS) // 1024 blocks -> 16 waves/CU

typedef float v2f __attribute__((ext_vector_type(2)));

__device__ __forceinline__ v2f splat2(float s) { v2f r; r.x = s; r.y = s; return r; }

// Monotone float<->uint for the atomic fallback path only.
__device__ __forceinline__ unsigned int enc_f32(float f) {
    unsigned int b = __float_as_uint(f);
    return (b & 0x80000000u) ? ~b : (b | 0x80000000u);
}
__device__ __forceinline__ float dec_f32(unsigned int e) {
    unsigned int b = (e & 0x80000000u) ? (e & 0x7fffffffu) : ~e;
    return __uint_as_float(b);
}

// ---------------- main kernel (templated epilogue) ----------------
// Per block: (batch, adv-chunk of 4096, ori-split of 128 pts).
// Thread owns 16 adv points packed as 8 float2 per coord (v_pk_fma_f32);
// iterates ori points 2 at a time via same-address LDS broadcast; two mins
// per adv point fold into v_min3_f32.  u = 0.5*|o|^2 - dot(a,o);
// d = ra + 2*u_min recovered in the epilogue (ra recomputed from regs).
template <bool ATOMIC>
__global__ __launch_bounds__(BLK) void chamfer_main(const float* __restrict__ adv,
                                                    const float* __restrict__ ori,
                                                    float* __restrict__ partial,
                                                    unsigned int* __restrict__ slots) {
    const int bx = blockIdx.x;
    const int b = bx >> 7;                 // 128 blocks per batch
    const int rem = bx & 127;
    const int advChunk = rem & (ADV_CHUNKS - 1);
    const int split = rem >> 1;
    const int t = threadIdx.x;

    __shared__ float4 opts[OCHUNK];
    const float* orib = ori + ((size_t)b * NPTS + (size_t)split * OCHUNK) * 3;
    if (t < OCHUNK) {
        float x = orib[3 * t + 0], y = orib[3 * t + 1], z = orib[3 * t + 2];
        opts[t] = make_float4(x, y, z, 0.5f * (x * x + y * y + z * z));
    }

    const float* advb = adv + (size_t)b * NPTS * 3;
    const int base = advChunk * ADV_PER_BLOCK;
    v2f ax[HALF_APT], ay[HALF_APT], az[HALF_APT];
    float um[APT];
#pragma unroll
    for (int m = 0; m < HALF_APT; m++) {
        int iA = base + t + m * BLK;
        int iB = iA + HALF_APT * BLK;
        ax[m].x = -advb[3 * iA + 0]; ax[m].y = -advb[3 * iB + 0];
        ay[m].x = -advb[3 * iA + 1]; ay[m].y = -advb[3 * iB + 1];
        az[m].x = -advb[3 * iA + 2]; az[m].y = -advb[3 * iB + 2];
        um[m] = FLT_MAX; um[m + HALF_APT] = FLT_MAX;
    }
    __syncthreads();

#pragma unroll 2
    for (int k = 0; k < OCHUNK; k += 2) {
        float4 o0 = opts[k], o1 = opts[k + 1];
        v2f x0 = splat2(o0.x), y0 = splat2(o0.y), z0 = splat2(o0.z), w0 = splat2(o0.w);
        v2f x1 = splat2(o1.x), y1 = splat2(o1.y), z1 = splat2(o1.z), w1 = splat2(o1.w);
#pragma unroll
        for (int m = 0; m < HALF_APT; m++) {
            v2f u0 = __builtin_elementwise_fma(ax[m], x0,
                     __builtin_elementwise_fma(ay[m], y0,
                     __builtin_elementwise_fma(az[m], z0, w0)));
            v2f u1 = __builtin_elementwise_fma(ax[m], x1,
                     __builtin_elementwise_fma(ay[m], y1,
                     __builtin_elementwise_fma(az[m], z1, w1)));
            um[m]            = fminf(fminf(um[m],            u0.x), u1.x);  // v_min3
            um[m + HALF_APT] = fminf(fminf(um[m + HALF_APT], u0.y), u1.y);  // v_min3
        }
    }

#pragma unroll
    for (int m = 0; m < HALF_APT; m++) {
        float raA = ax[m].x * ax[m].x + ay[m].x * ay[m].x + az[m].x * az[m].x;
        float raB = ax[m].y * ax[m].y + ay[m].y * ay[m].y + az[m].y * az[m].y;
        float dA = fmaf(2.0f, um[m], raA);
        float dB = fmaf(2.0f, um[m + HALF_APT], raB);
        int sA = base + t + m * BLK;
        int sB = sA + HALF_APT * BLK;
        if (ATOMIC) {
            atomicMin(&slots[b * NPTS + sA], enc_f32(dA));
            atomicMin(&slots[b * NPTS + sB], enc_f32(dB));
        } else {
            float* pb = partial + (size_t)split * TOTAL + (size_t)b * NPTS;
            pb[sA] = dA;
            pb[sB] = dB;
        }
    }
}

// ---------------- single fused reduce (partials path) ----------------
__global__ __launch_bounds__(BLK) void reduce_partial(const float* __restrict__ partial,
                                                      const float* __restrict__ w,
                                                      float* __restrict__ out) {
    int g = blockIdx.x * BLK + threadIdx.x;
    float m = FLT_MAX;
#pragma unroll 8
    for (int s = 0; s < OSPLIT; s++) m = fminf(m, partial[(size_t)s * TOTAL + g]);
    float v = m * w[g >> 13];                 // 8192 points per batch
    __shared__ float red[BLK];
    red[threadIdx.x] = v;
    __syncthreads();
    for (int s = BLK / 2; s > 0; s >>= 1) {
        if (threadIdx.x < s) red[threadIdx.x] += red[threadIdx.x + s];
        __syncthreads();
    }
    if (threadIdx.x == 0) atomicAdd(out, red[0] * (1.0f / (float)TOTAL));
}

// ---------------- atomic fallback path helpers ----------------
__global__ __launch_bounds__(BLK) void init_slots(unsigned int* __restrict__ slots) {
    slots[blockIdx.x * BLK + threadIdx.x] = 0xFFFFFFFFu;  // +inf
}

__global__ __launch_bounds__(BLK) void reduce_slots(const unsigned int* __restrict__ slots,
                                                    const float* __restrict__ w,
                                                    float* __restrict__ out) {
    int g = blockIdx.x * BLK + threadIdx.x;
    float v = dec_f32(slots[g]) * w[g >> 13];
    __shared__ float red[BLK];
    red[threadIdx.x] = v;
    __syncthreads();
    for (int s = BLK / 2; s > 0; s >>= 1) {
        if (threadIdx.x < s) red[threadIdx.x] += red[threadIdx.x + s];
        __syncthreads();
    }
    if (threadIdx.x == 0) atomicAdd(out, red[0] * (1.0f / (float)TOTAL));
}

extern "C" void kernel_launch(void* const* d_in, const int* in_sizes, int n_in,
                              void* d_out, int out_size, void* d_ws, size_t ws_size,
                              hipStream_t stream) {
    const float* adv = (const float*)d_in[0];   // [8,8192,3] f32
    const float* ori = (const float*)d_in[1];   // [8,8192,3] f32
    const float* w   = (const float*)d_in[2];   // [8] f32
    float* out = (float*)d_out;

    const size_t need = (size_t)OSPLIT * TOTAL * sizeof(float);  // 16 MB
    hipMemsetAsync(out, 0, sizeof(float), stream);               // capturable

    if (ws_size >= need) {
        float* partial = (float*)d_ws;
        hipLaunchKernelGGL((chamfer_main<false>), dim3(GRID_MAIN), dim3(BLK), 0, stream,
                           adv, ori, partial, (unsigned int*)nullptr);
        hipLaunchKernelGGL(reduce_partial, dim3(TOTAL / BLK), dim3(BLK), 0, stream,
                           partial, w, out);
    } else {
        unsigned int* slots = (unsigned int*)d_ws;               // 256 KB
        hipLaunchKernelGGL(init_slots, dim3(TOTAL / BLK), dim3(BLK), 0, stream, slots);
        hipLaunchKernelGGL((chamfer_main<true>), dim3(GRID_MAIN), dim3(BLK), 0, stream,
                           adv, ori, (float*)nullptr, slots);
        hipLaunchKernelGGL(reduce_slots, dim3(TOTAL / BLK), dim3(BLK), 0, stream,
                           slots, w, out);
    }
}